// Round 12
// baseline (70.913 us; speedup 1.0000x reference)
//
#include <hip/hip_runtime.h>

typedef short s16x8 __attribute__((ext_vector_type(8)));
typedef float f32x4 __attribute__((ext_vector_type(4)));

constexpr int F  = 24;
constexpr int NP = 276;   // F*(F-1)/2
constexpr int E  = 64;
constexpr int TS = 68;    // LDS transpose stripe row stride (floats): 68 % 32 == 4

__device__ __forceinline__ unsigned short f2bf(float f) {
    unsigned int u = __builtin_bit_cast(unsigned int, f);
    return (unsigned short)((u + 0x7FFFu + ((u >> 16) & 1u)) >> 16);  // RNE
}

// ---- prepass: W[p] fp32 -> bf16 packed in the EXACT swizzled LDS image ----
__global__ __launch_bounds__(256)
void w_prepass(const float* __restrict__ W, unsigned int* __restrict__ wsW)
{
    const int p   = blockIdx.x;
    const int tid = threadIdx.x;
    const float* Wp = W + (size_t)p * E * E;
    unsigned int* dst = wsW + (size_t)p * 2048;
    #pragma unroll
    for (int it = 0; it < 8; ++it) {
        int q  = tid + it * 256;
        int f  = q & 63;
        int e2 = q >> 6;
        float w0 = Wp[(2 * e2) * E + f];
        float w1 = Wp[(2 * e2 + 1) * E + f];
        unsigned int pk = (unsigned int)f2bf(w0) | ((unsigned int)f2bf(w1) << 16);
        dst[f * 32 + (e2 ^ ((f & 7) << 2))] = pk;
    }
}

__global__ __launch_bounds__(256)
void bilinear_kernel(const float* __restrict__ x, const float* __restrict__ W,
                     float* __restrict__ out,
                     const unsigned int* __restrict__ wsW, const int use_ws)
{
    __shared__ unsigned int BtU[2048];     // 8 KB: W[p]^T bf16, XOR-swizzled
    __shared__ float Tbuf[4][16 * TS];     // 17.4 KB: per-wave transpose stripes

    // ---- XCD swizzle: block = 1 pair x 512 batches (XCD's full window) ----
    const int bid = blockIdx.x;
    const int xcd = bid & 7;
    const int p   = bid >> 3;              // 0..275
    const int b0  = xcd * 512;

    const int tid  = threadIdx.x;
    const int wv   = tid >> 6;
    const int ln   = tid & 63;
    const int lrow = ln & 15;
    const int lq   = ln >> 4;

    // decode pair (i, j)
    int i = 0, rem = p;
    while (rem >= F - 1 - i) { rem -= F - 1 - i; ++i; }
    const int j = i + 1 + rem;

    // ---- stage W[p] image: linear copy from prepass (fast path) or
    //      convert from fp32 in-kernel (fallback, R11 verbatim) ----
    if (use_ws) {
        const unsigned int* src = wsW + (size_t)p * 2048;
        #pragma unroll
        for (int it = 0; it < 8; ++it)
            BtU[tid + it * 256] = src[tid + it * 256];
    } else {
        const float* Wp = W + (size_t)p * E * E;
        #pragma unroll
        for (int it = 0; it < 8; ++it) {
            int q  = tid + it * 256;
            int f  = q & 63;
            int e2 = q >> 6;
            float w0 = Wp[(2 * e2) * E + f];
            float w1 = Wp[(2 * e2 + 1) * E + f];
            unsigned int pk = (unsigned int)f2bf(w0) | ((unsigned int)f2bf(w1) << 16);
            BtU[f * 32 + (e2 ^ ((f & 7) << 2))] = pk;
        }
    }
    __syncthreads();

    const unsigned short* Bts = reinterpret_cast<const unsigned short*>(BtU);

    // B fragments (W^T), register-resident
    s16x8 bfrag[4][2];
    #pragma unroll
    for (int n = 0; n < 4; ++n) {
        int fc = n * 16 + lrow;
        #pragma unroll
        for (int kk = 0; kk < 2; ++kk) {
            int k0 = kk * 32 + lq * 8;
            int sidx = fc * 64 + (k0 ^ ((fc & 7) << 3));
            bfrag[n][kk] = *reinterpret_cast<const s16x8*>(&Bts[sidx]);
        }
    }

    float* stripe = Tbuf[wv];   // this wave's private 16-row stripe

    #pragma unroll 1
    for (int s = 0; s < 8; ++s) {
        const int mbase = s * 64 + wv * 16;

        // A fragments straight from global (L2-hot after swizzle)
        s16x8 afrag[2];
        #pragma unroll
        for (int kk = 0; kk < 2; ++kk) {
            int b  = b0 + mbase + lrow;
            int k0 = kk * 32 + lq * 8;
            const float4* ap = reinterpret_cast<const float4*>(
                x + ((size_t)b * F + i) * E + k0);
            float4 lo = ap[0], hi = ap[1];
            s16x8 a;
            a[0] = (short)f2bf(lo.x); a[1] = (short)f2bf(lo.y);
            a[2] = (short)f2bf(lo.z); a[3] = (short)f2bf(lo.w);
            a[4] = (short)f2bf(hi.x); a[5] = (short)f2bf(hi.y);
            a[6] = (short)f2bf(hi.z); a[7] = (short)f2bf(hi.w);
            afrag[kk] = a;
        }

        f32x4 acc[4];
        #pragma unroll
        for (int n = 0; n < 4; ++n) {
            acc[n] = (f32x4){0.f, 0.f, 0.f, 0.f};
            acc[n] = __builtin_amdgcn_mfma_f32_16x16x32_bf16(afrag[0], bfrag[n][0], acc[n], 0, 0, 0);
            acc[n] = __builtin_amdgcn_mfma_f32_16x16x32_bf16(afrag[1], bfrag[n][1], acc[n], 0, 0, 0);
        }

        // ---- scatter acc into the wave-private LDS stripe (2-way banks) ----
        #pragma unroll
        for (int n = 0; n < 4; ++n)
            #pragma unroll
            for (int r = 0; r < 4; ++r)
                stripe[(lq * 4 + r) * TS + n * 16 + lrow] = acc[n][r];
        // no barrier: producer and consumer are the same wave

        // ---- gather row-major, * xj (float4), NT dwordx4 store ----
        #pragma unroll
        for (int c = 0; c < 4; ++c) {
            const int rloc = c * 4 + lq;                 // 0..15
            const f32x4 v = *reinterpret_cast<const f32x4*>(
                &stripe[rloc * TS + lrow * 4]);
            const int b = b0 + mbase + rloc;
            const f32x4 xj = *reinterpret_cast<const f32x4*>(
                x + ((size_t)b * F + j) * E + lrow * 4);
            __builtin_nontemporal_store(v * xj, reinterpret_cast<f32x4*>(
                out + ((size_t)b * NP + p) * E + lrow * 4));
        }
    }
}

extern "C" void kernel_launch(void* const* d_in, const int* in_sizes, int n_in,
                              void* d_out, int out_size, void* d_ws, size_t ws_size,
                              hipStream_t stream)
{
    const float* x = (const float*)d_in[0];
    const float* W = (const float*)d_in[1];
    float* out = (float*)d_out;

    const size_t ws_needed = (size_t)NP * 2048 * 4;   // 2.26 MB
    const int use_ws = (ws_size >= ws_needed && d_ws != nullptr) ? 1 : 0;

    if (use_ws)
        w_prepass<<<NP, 256, 0, stream>>>(W, (unsigned int*)d_ws);

    dim3 grid(NP * 8, 1, 1);   // 2208 = 8 XCDs x 276 pairs
    bilinear_kernel<<<grid, 256, 0, stream>>>(x, W, out,
                                              (const unsigned int*)d_ws, use_ws);
}

// Round 13
// 67.675 us; speedup vs baseline: 1.0478x; 1.0478x over previous
//
#include <hip/hip_runtime.h>

typedef short s16x8 __attribute__((ext_vector_type(8)));
typedef float f32x4 __attribute__((ext_vector_type(4)));

constexpr int F  = 24;
constexpr int NP = 276;   // F*(F-1)/2
constexpr int E  = 64;
constexpr int TS = 68;    // LDS transpose stripe row stride (floats): 68 % 32 == 4

__device__ __forceinline__ unsigned short f2bf(float f) {
    unsigned int u = __builtin_bit_cast(unsigned int, f);
    return (unsigned short)((u + 0x7FFFu + ((u >> 16) & 1u)) >> 16);  // RNE
}

__global__ __launch_bounds__(256)
void bilinear_kernel(const float* __restrict__ x, const float* __restrict__ W,
                     float* __restrict__ out)
{
    __shared__ unsigned int BtU[2048];     // 8 KB: W[p]^T bf16, XOR-swizzled
    __shared__ float Tbuf[4][16 * TS];     // 17.4 KB: per-wave transpose stripes

    // ---- XCD swizzle: block = 1 pair x 512 batches (the XCD's full window)
    // grid 2208 = 8 XCD x 276 pairs; W staged ONCE per (XCD, pair).
    const int bid = blockIdx.x;
    const int xcd = bid & 7;
    const int p   = bid >> 3;              // 0..275
    const int b0  = xcd * 512;

    const int tid  = threadIdx.x;
    const int wv   = tid >> 6;
    const int ln   = tid & 63;
    const int lrow = ln & 15;
    const int lq   = ln >> 4;

    // decode pair (i, j)
    int i = 0, rem = p;
    while (rem >= F - 1 - i) { rem -= F - 1 - i; ++i; }
    const int j = i + 1 + rem;

    // ---- stage W[p]^T into LDS as bf16, XOR-swizzled ----
    const float* Wp = W + (size_t)p * E * E;
    #pragma unroll
    for (int it = 0; it < 8; ++it) {
        int q  = tid + it * 256;
        int f  = q & 63;
        int e2 = q >> 6;
        float w0 = Wp[(2 * e2) * E + f];
        float w1 = Wp[(2 * e2 + 1) * E + f];
        unsigned int pk = (unsigned int)f2bf(w0) | ((unsigned int)f2bf(w1) << 16);
        BtU[f * 32 + (e2 ^ ((f & 7) << 2))] = pk;
    }
    __syncthreads();

    const unsigned short* Bts = reinterpret_cast<const unsigned short*>(BtU);

    // B fragments (W^T), register-resident
    s16x8 bfrag[4][2];
    #pragma unroll
    for (int n = 0; n < 4; ++n) {
        int fc = n * 16 + lrow;
        #pragma unroll
        for (int kk = 0; kk < 2; ++kk) {
            int k0 = kk * 32 + lq * 8;
            int sidx = fc * 64 + (k0 ^ ((fc & 7) << 3));
            bfrag[n][kk] = *reinterpret_cast<const s16x8*>(&Bts[sidx]);
        }
    }

    float* stripe = Tbuf[wv];   // this wave's private 16-row stripe

    #pragma unroll 1
    for (int s = 0; s < 8; ++s) {
        const int mbase = s * 64 + wv * 16;

        // A fragments straight from global (L2-hot after swizzle)
        s16x8 afrag[2];
        #pragma unroll
        for (int kk = 0; kk < 2; ++kk) {
            int b  = b0 + mbase + lrow;
            int k0 = kk * 32 + lq * 8;
            const float4* ap = reinterpret_cast<const float4*>(
                x + ((size_t)b * F + i) * E + k0);
            float4 lo = ap[0], hi = ap[1];
            s16x8 a;
            a[0] = (short)f2bf(lo.x); a[1] = (short)f2bf(lo.y);
            a[2] = (short)f2bf(lo.z); a[3] = (short)f2bf(lo.w);
            a[4] = (short)f2bf(hi.x); a[5] = (short)f2bf(hi.y);
            a[6] = (short)f2bf(hi.z); a[7] = (short)f2bf(hi.w);
            afrag[kk] = a;
        }

        f32x4 acc[4];
        #pragma unroll
        for (int n = 0; n < 4; ++n) {
            acc[n] = (f32x4){0.f, 0.f, 0.f, 0.f};
            acc[n] = __builtin_amdgcn_mfma_f32_16x16x32_bf16(afrag[0], bfrag[n][0], acc[n], 0, 0, 0);
            acc[n] = __builtin_amdgcn_mfma_f32_16x16x32_bf16(afrag[1], bfrag[n][1], acc[n], 0, 0, 0);
        }

        // ---- scatter acc into the wave-private LDS stripe (2-way banks) ----
        #pragma unroll
        for (int n = 0; n < 4; ++n)
            #pragma unroll
            for (int r = 0; r < 4; ++r)
                stripe[(lq * 4 + r) * TS + n * 16 + lrow] = acc[n][r];
        // no barrier: producer and consumer are the same wave

        // ---- gather row-major, * xj (float4), NT dwordx4 store ----
        #pragma unroll
        for (int c = 0; c < 4; ++c) {
            const int rloc = c * 4 + lq;                 // 0..15
            const f32x4 v = *reinterpret_cast<const f32x4*>(
                &stripe[rloc * TS + lrow * 4]);
            const int b = b0 + mbase + rloc;
            const f32x4 xj = *reinterpret_cast<const f32x4*>(
                x + ((size_t)b * F + j) * E + lrow * 4);
            __builtin_nontemporal_store(v * xj, reinterpret_cast<f32x4*>(
                out + ((size_t)b * NP + p) * E + lrow * 4));
        }
    }
}

extern "C" void kernel_launch(void* const* d_in, const int* in_sizes, int n_in,
                              void* d_out, int out_size, void* d_ws, size_t ws_size,
                              hipStream_t stream)
{
    const float* x = (const float*)d_in[0];
    const float* W = (const float*)d_in[1];
    float* out = (float*)d_out;
    dim3 grid(NP * 8, 1, 1);   // 2208 = 8 XCDs x 276 pairs
    bilinear_kernel<<<grid, 256, 0, stream>>>(x, W, out);
}